// Round 14
// baseline (384.456 us; speedup 1.0000x reference)
//
#include <hip/hip_runtime.h>
#include <stdint.h>

#define GAS __attribute__((address_space(1)))
#define LAS __attribute__((address_space(3)))

typedef __attribute__((ext_vector_type(8))) short short8;
typedef __attribute__((ext_vector_type(16))) float f32x16;

static constexpr int N_TOK = 2048;
static constexpr int DM    = 1024;
static constexpr int DF    = 4096;
static constexpr int KP    = 4;

// ---------- helpers ----------
__device__ inline unsigned short f2bf(float f) {
  union { float f; uint32_t u; } v; v.f = f;
  uint32_t u = v.u;
  u += 0x7FFFu + ((u >> 16) & 1u);   // RNE
  return (unsigned short)(u >> 16);
}

__device__ inline uint32_t pk_bf(float lo, float hi) {
  union { float f; uint32_t u; } a, b; a.f = lo; b.f = hi;
  uint32_t ul = a.u + 0x7FFFu + ((a.u >> 16) & 1u);
  uint32_t uh = b.u + 0x7FFFu + ((b.u >> 16) & 1u);
  return (ul >> 16) | (uh & 0xFFFF0000u);
}

// gelu(v)*g, sigmoid form, overflow-safe
__device__ inline float gelu_gate(float v, float g) {
  float t0 = v * v;
  float u  = v * __builtin_fmaf(t0, -0.10294456f, -2.3022539f);
  float e  = __builtin_amdgcn_exp2f(u);
  float r  = __builtin_amdgcn_rcpf(1.0f + e);
  return v * g * r;
}

__device__ inline void gld16(const void* g, void* l) {
  __builtin_amdgcn_global_load_lds((const GAS void*)g, (LAS void*)l, 16, 0, 0);
}

// ---------- setup: build_w1 (blocks [0,1024)) | prep (blocks [1024,1536)) ----------
__global__ __launch_bounds__(256) void setup_kernel(
    const float* __restrict__ tokens, const float* __restrict__ pb,
    const float* __restrict__ c11, const float* __restrict__ c12,
    float* __restrict__ gates, unsigned short* __restrict__ xb,
    unsigned short* __restrict__ w1t) {
  __shared__ __align__(16) float sh[8896];   // 512 + 16*524 = 8896 floats
  const int blk = blockIdx.x;
  const int t = threadIdx.x;
  if (blk < 1024) {
    // ---- build_w1: w1t[k][f=x*64+y][d=a*32+b] ----
    const int k = blk >> 8, x = (blk >> 2) & 63, y0 = (blk & 3) * 16;
    float* s1  = sh;          // [a(32)][r(16)]
    float* s2T = sh + 512;    // [y(16)][stride 524], idx = r*32+b
    if (t < 128) {
      int a = t >> 2, rq = (t & 3) * 4;
      *(float4*)(s1 + a * 16 + rq) =
          *(const float4*)(c11 + (((size_t)(k * 32 + a)) * 64 + x) * 16 + rq);
    }
#pragma unroll
    for (int j = 0; j < 8; ++j) {
      int i = t + j * 256;              // [0,2048)
      int rb = i >> 2, yy0 = (i & 3) * 4;
      float4 v = *(const float4*)(c12 + (size_t)(k * 16) * 2048 + (size_t)rb * 64 + y0 + yy0);
      s2T[(yy0 + 0) * 524 + rb] = v.x;
      s2T[(yy0 + 1) * 524 + rb] = v.y;
      s2T[(yy0 + 2) * 524 + rb] = v.z;
      s2T[(yy0 + 3) * 524 + rb] = v.w;
    }
    __syncthreads();
    const int a = t >> 3, b0 = (t & 7) * 4;   // d = 4t (contiguous stores)
    float4 s1q[4];
#pragma unroll
    for (int q = 0; q < 4; ++q) s1q[q] = *(const float4*)(s1 + a * 16 + q * 4);
    const float* a0s = (const float*)s1q;
    for (int y = 0; y < 16; ++y) {
      const float* s2y = s2T + y * 524;
      float4 acc = {0.f, 0.f, 0.f, 0.f};
#pragma unroll
      for (int r = 0; r < 16; ++r) {
        float cv = a0s[r];
        float4 bv = *(const float4*)(s2y + r * 32 + b0);
        acc.x = __builtin_fmaf(cv, bv.x, acc.x);
        acc.y = __builtin_fmaf(cv, bv.y, acc.y);
        acc.z = __builtin_fmaf(cv, bv.z, acc.z);
        acc.w = __builtin_fmaf(cv, bv.w, acc.w);
      }
      ushort4 o; o.x = f2bf(acc.x); o.y = f2bf(acc.y); o.z = f2bf(acc.z); o.w = f2bf(acc.w);
      *(ushort4*)(w1t + ((size_t)k * DF + x * 64 + y0 + y) * DM + t * 4) = o;
    }
  } else {
    // ---- prep: gates + bf16 cast ----
    const int wave = t >> 6, lane = t & 63;
    const int n = (blk - 1024) * 4 + wave;
    float s0 = 0.f, s1v = 0.f, s2v = 0.f, s3v = 0.f;
    const float4* tr = (const float4*)(tokens + (size_t)n * DM);
#pragma unroll
    for (int j = 0; j < 4; ++j) {
      int idx = j * 64 + lane;
      float4 tv = tr[idx];
      ushort4 b;
      b.x = f2bf(tv.x); b.y = f2bf(tv.y); b.z = f2bf(tv.z); b.w = f2bf(tv.w);
      *(ushort4*)(xb + (size_t)n * DM + idx * 4) = b;
      float4 q;
      q = ((const float4*)(pb + 0 * DM))[idx]; s0  += tv.x*q.x + tv.y*q.y + tv.z*q.z + tv.w*q.w;
      q = ((const float4*)(pb + 1 * DM))[idx]; s1v += tv.x*q.x + tv.y*q.y + tv.z*q.z + tv.w*q.w;
      q = ((const float4*)(pb + 2 * DM))[idx]; s2v += tv.x*q.x + tv.y*q.y + tv.z*q.z + tv.w*q.w;
      q = ((const float4*)(pb + 3 * DM))[idx]; s3v += tv.x*q.x + tv.y*q.y + tv.z*q.z + tv.w*q.w;
    }
#pragma unroll
    for (int off = 32; off > 0; off >>= 1) {
      s0  += __shfl_xor(s0, off);
      s1v += __shfl_xor(s1v, off);
      s2v += __shfl_xor(s2v, off);
      s3v += __shfl_xor(s3v, off);
    }
    if (lane == 0) {
      float m = fmaxf(fmaxf(s0, s1v), fmaxf(s2v, s3v));
      float e0 = __expf(s0 - m), e1 = __expf(s1v - m), e2 = __expf(s2v - m), e3 = __expf(s3v - m);
      float inv = 1.0f / (e0 + e1 + e2 + e3);
      float4 g; g.x = e0 * inv; g.y = e1 * inv; g.z = e2 * inv; g.w = e3 * inv;
      *(float4*)(gates + n * 4) = g;
    }
  }
}

// ---------- GEMM1 fused with build_w2 ----------
// z==0 (dispatched first): build_w2 using 512 blocks (k,x,y-quad of 8), 32 KB LDS.
// z in [1,4]: gemm1 kp=z-1, 128x128 tile, BK=64, mfma 32x32x16, XOR swizzle.
__global__ __launch_bounds__(256) void gemm1_fused(
    const unsigned short* __restrict__ xb, const unsigned short* __restrict__ w1t,
    const float* __restrict__ gates, unsigned short* __restrict__ hg,
    const float* __restrict__ c21, const float* __restrict__ c22,
    unsigned short* __restrict__ w2t) {
  __shared__ __align__(16) float smf[8192];   // 32 KB shared by both branches
  const int t = threadIdx.x;
  if (blockIdx.z == 0) {
    // ---- build_w2: w2t[k][d=x*32+y][f=a*64+b] ----
    const int bid = blockIdx.y * 16 + blockIdx.x;   // [0,512)
    const int k = bid >> 7, rest = bid & 127;
    const int x = rest >> 2, y0 = (rest & 3) * 8;
    float* s2T = smf;          // [y(8)][stride 1024], idx = r*64+b (y uniform per wave)
#pragma unroll
    for (int j = 0; j < 8; ++j) {
      int i = t + j * 256;              // [0,2048)
      int rb = i >> 1, yy0 = (i & 1) * 4;   // rb in [0,1024)
      float4 v = *(const float4*)(c22 + (size_t)k * 32768 + (size_t)rb * 32 + y0 + yy0);
      s2T[(yy0 + 0) * 1024 + rb] = v.x;
      s2T[(yy0 + 1) * 1024 + rb] = v.y;
      s2T[(yy0 + 2) * 1024 + rb] = v.z;
      s2T[(yy0 + 3) * 1024 + rb] = v.w;
    }
    __syncthreads();
    const int b0 = (t & 15) * 4;
#pragma unroll
    for (int jj = 0; jj < 4; ++jj) {
      const int a = (t >> 4) + jj * 16;   // f = 4t + jj*1024
      float4 s1q[4];
      const float* abase = c21 + (((size_t)(k * 64 + a)) * 32 + x) * 16;
#pragma unroll
      for (int q = 0; q < 4; ++q) s1q[q] = *(const float4*)(abase + q * 4);
      const float* a0s = (const float*)s1q;
      for (int y = 0; y < 8; ++y) {
        const float* s2y = s2T + y * 1024;
        float4 acc = {0.f, 0.f, 0.f, 0.f};
#pragma unroll
        for (int r = 0; r < 16; ++r) {
          float cv = a0s[r];
          float4 bv = *(const float4*)(s2y + r * 64 + b0);
          acc.x = __builtin_fmaf(cv, bv.x, acc.x);
          acc.y = __builtin_fmaf(cv, bv.y, acc.y);
          acc.z = __builtin_fmaf(cv, bv.z, acc.z);
          acc.w = __builtin_fmaf(cv, bv.w, acc.w);
        }
        ushort4 o; o.x = f2bf(acc.x); o.y = f2bf(acc.y); o.z = f2bf(acc.z); o.w = f2bf(acc.w);
        *(ushort4*)(w2t + ((size_t)k * DM + x * 32 + y0 + y) * DF + t * 4 + jj * 1024) = o;
      }
    }
    return;
  }
  // ---- gemm1: hg[k][n][f] = bf16(gelu(x@W1[k])*gate) ----
  unsigned short* As = (unsigned short*)smf;          // [128][64] xb tile
  unsigned short* Bs = (unsigned short*)smf + 8192;   // [128][64] w1t tile
  const int lane = t & 63, wv = t >> 6;
  const int m0 = blockIdx.x * 128;   // token tile
  const int f0 = blockIdx.y * 128;   // f tile
  const int kp = blockIdx.z - 1;
  const unsigned short* B = w1t + (size_t)kp * DF * DM;
  f32x16 acc[2][2] = {};             // [f-frag][token-frag]
  const int srow = t >> 3;
  const int sbase = ((t & 7) ^ (srow & 7) ^ (srow >> 3)) * 8;  // elements, even i
  const int wfrow = (wv >> 1) * 64, wtcol = (wv & 1) * 64;
  const int l31 = lane & 31, khalf = lane >> 5;
  const int rsw = (l31 & 7) ^ (l31 >> 3);   // read swizzle base
  char* AsB = (char*)As;
  char* BsB = (char*)Bs;
  for (int k0 = 0; k0 < DM; k0 += 64) {
#pragma unroll
    for (int i = 0; i < 4; ++i) {
      int row = i * 32 + srow;
      int sc = sbase ^ ((i & 1) * 32);
      gld16(xb + (size_t)(m0 + row) * DM + k0 + sc, AsB + i * 4096 + t * 16);
      gld16(B + (size_t)(f0 + row) * DM + k0 + sc, BsB + i * 4096 + t * 16);
    }
    __syncthreads();
#pragma unroll
    for (int s = 0; s < 4; ++s) {
      const int lc = s * 2 + khalf;
      short8 a[2], b[2];
#pragma unroll
      for (int mi = 0; mi < 2; ++mi) {
        const int pc = ((lc ^ rsw ^ (mi * 4)) & 7) * 8;
        a[mi] = *(const short8*)(Bs + (wfrow + mi * 32 + l31) * 64 + pc);
      }
#pragma unroll
      for (int ni = 0; ni < 2; ++ni) {
        const int pc = ((lc ^ rsw ^ (ni * 4)) & 7) * 8;
        b[ni] = *(const short8*)(As + (wtcol + ni * 32 + l31) * 64 + pc);
      }
#pragma unroll
      for (int mi = 0; mi < 2; ++mi)
#pragma unroll
        for (int ni = 0; ni < 2; ++ni)
          acc[mi][ni] = __builtin_amdgcn_mfma_f32_32x32x16_bf16(a[mi], b[ni], acc[mi][ni], 0, 0, 0);
    }
    __syncthreads();
  }
  // epilogue: r-group gq holds 4 consecutive f at f = base + 8*gq
  unsigned short* H = hg + (size_t)kp * N_TOK * DF;
  const int rbase = 4 * khalf;
#pragma unroll
  for (int ni = 0; ni < 2; ++ni) {
    int n_g = m0 + wtcol + ni * 32 + l31;
    float g = gates[n_g * 4 + kp];
    unsigned short* hrow = H + (size_t)n_g * DF + f0;
#pragma unroll
    for (int mi = 0; mi < 2; ++mi) {
      int fbase = wfrow + mi * 32 + rbase;
#pragma unroll
      for (int gq = 0; gq < 4; ++gq) {
        float r0 = gelu_gate(acc[mi][ni][4 * gq + 0], g);
        float r1 = gelu_gate(acc[mi][ni][4 * gq + 1], g);
        float r2 = gelu_gate(acc[mi][ni][4 * gq + 2], g);
        float r3 = gelu_gate(acc[mi][ni][4 * gq + 3], g);
        uint2 p; p.x = pk_bf(r0, r1); p.y = pk_bf(r2, r3);
        *(uint2*)(hrow + fbase + 8 * gq) = p;
      }
    }
  }
}

// ---------- GEMM2: part[k][n][d] = (1+pw[k,d]) * (hg[k]@W2[k])[n,d] ----------
__global__ __launch_bounds__(256) void gemm2(
    const unsigned short* __restrict__ hg, const unsigned short* __restrict__ w2t,
    const float* __restrict__ pw, float* __restrict__ part) {
  __shared__ __align__(16) unsigned short As[128 * 64];  // hg tile  [token-row][k]
  __shared__ __align__(16) unsigned short Bs[128 * 64];  // w2t tile [d-row][k]
  const int t = threadIdx.x, lane = t & 63, wv = t >> 6;
  const int m0 = blockIdx.x * 128;   // token tile
  const int n0 = blockIdx.y * 128;   // d tile
  const int kp = blockIdx.z;
  const unsigned short* A = hg + (size_t)kp * N_TOK * DF;
  const unsigned short* B = w2t + (size_t)kp * DM * DF;
  f32x16 acc[2][2] = {};             // [d-frag][token-frag]
  const int srow = t >> 3;
  const int sbase = ((t & 7) ^ (srow & 7) ^ (srow >> 3)) * 8;
  const int wdrow = (wv >> 1) * 64, wtcol = (wv & 1) * 64;
  const int l31 = lane & 31, khalf = lane >> 5;
  const int rsw = (l31 & 7) ^ (l31 >> 3);
  char* AsB = (char*)As;
  char* BsB = (char*)Bs;
  for (int k0 = 0; k0 < DF; k0 += 64) {
#pragma unroll
    for (int i = 0; i < 4; ++i) {
      int row = i * 32 + srow;
      int sc = sbase ^ ((i & 1) * 32);
      gld16(A + (size_t)(m0 + row) * DF + k0 + sc, AsB + i * 4096 + t * 16);
      gld16(B + (size_t)(n0 + row) * DF + k0 + sc, BsB + i * 4096 + t * 16);
    }
    __syncthreads();
#pragma unroll
    for (int s = 0; s < 4; ++s) {
      const int lc = s * 2 + khalf;
      short8 a[2], b[2];
#pragma unroll
      for (int mi = 0; mi < 2; ++mi) {
        const int pc = ((lc ^ rsw ^ (mi * 4)) & 7) * 8;
        a[mi] = *(const short8*)(Bs + (wdrow + mi * 32 + l31) * 64 + pc);
      }
#pragma unroll
      for (int ni = 0; ni < 2; ++ni) {
        const int pc = ((lc ^ rsw ^ (ni * 4)) & 7) * 8;
        b[ni] = *(const short8*)(As + (wtcol + ni * 32 + l31) * 64 + pc);
      }
#pragma unroll
      for (int mi = 0; mi < 2; ++mi)
#pragma unroll
        for (int ni = 0; ni < 2; ++ni)
          acc[mi][ni] = __builtin_amdgcn_mfma_f32_32x32x16_bf16(a[mi], b[ni], acc[mi][ni], 0, 0, 0);
    }
    __syncthreads();
  }
  float* P = part + (size_t)kp * N_TOK * DM;
  const int rbase = 4 * khalf;
  float4 pwv[2][4];
#pragma unroll
  for (int mi = 0; mi < 2; ++mi)
#pragma unroll
    for (int gq = 0; gq < 4; ++gq) {
      float4 w = *(const float4*)(pw + kp * DM + n0 + wdrow + mi * 32 + rbase + 8 * gq);
      pwv[mi][gq].x = 1.0f + w.x; pwv[mi][gq].y = 1.0f + w.y;
      pwv[mi][gq].z = 1.0f + w.z; pwv[mi][gq].w = 1.0f + w.w;
    }
#pragma unroll
  for (int ni = 0; ni < 2; ++ni) {
    int tok = m0 + wtcol + ni * 32 + l31;
    float* prow = P + (size_t)tok * DM + n0;
#pragma unroll
    for (int mi = 0; mi < 2; ++mi) {
      int dbase = wdrow + mi * 32 + rbase;
#pragma unroll
      for (int gq = 0; gq < 4; ++gq) {
        float4 o;
        o.x = pwv[mi][gq].x * acc[mi][ni][4 * gq + 0];
        o.y = pwv[mi][gq].y * acc[mi][ni][4 * gq + 1];
        o.z = pwv[mi][gq].z * acc[mi][ni][4 * gq + 2];
        o.w = pwv[mi][gq].w * acc[mi][ni][4 * gq + 3];
        *(float4*)(prow + dbase + 8 * gq) = o;
      }
    }
  }
}

// ---------- reduce partials over k ----------
__global__ __launch_bounds__(256) void reduce_k(
    const float* __restrict__ part, float* __restrict__ out) {
  const size_t i = ((size_t)blockIdx.x * 256 + threadIdx.x) * 4;
  const size_t S = (size_t)N_TOK * DM;
  float4 a = *(const float4*)(part + i);
  float4 b = *(const float4*)(part + S + i);
  float4 c = *(const float4*)(part + 2 * S + i);
  float4 d = *(const float4*)(part + 3 * S + i);
  float4 r;
  r.x = a.x + b.x + c.x + d.x;
  r.y = a.y + b.y + c.y + d.y;
  r.z = a.z + b.z + c.z + d.z;
  r.w = a.w + b.w + c.w + d.w;
  *(float4*)(out + i) = r;
}

// ---------- launcher ----------
extern "C" void kernel_launch(void* const* d_in, const int* in_sizes, int n_in,
                              void* d_out, int out_size, void* d_ws, size_t ws_size,
                              hipStream_t stream) {
  const float* tokens = (const float*)d_in[0];
  const float* f1c1   = (const float*)d_in[1];
  const float* f1c2   = (const float*)d_in[2];
  const float* f2c1   = (const float*)d_in[3];
  const float* f2c2   = (const float*)d_in[4];
  const float* pb     = (const float*)d_in[5];
  const float* pw     = (const float*)d_in[6];
  float* out = (float*)d_out;

  char* ws = (char*)d_ws;
  unsigned short* xb  = (unsigned short*)(ws);                  //   4 MB
  unsigned short* w1t = (unsigned short*)(ws + (4ull  << 20));  //  32 MB (dead after gemm1)
  float*          part = (float*)(ws + (4ull << 20));           //  32 MB (reuses w1t)
  unsigned short* w2t = (unsigned short*)(ws + (36ull << 20));  //  32 MB
  unsigned short* hg  = (unsigned short*)(ws + (68ull << 20));  //  64 MB
  float*          gates = (float*)(ws + (132ull << 20));        //  32 KB

  hipLaunchKernelGGL(setup_kernel, dim3(1536), dim3(256), 0, stream,
                     tokens, pb, f1c1, f1c2, gates, xb, w1t);
  hipLaunchKernelGGL(gemm1_fused, dim3(16, 32, KP + 1), dim3(256), 0, stream,
                     xb, w1t, gates, hg, f2c1, f2c2, w2t);
  hipLaunchKernelGGL(gemm2, dim3(16, 8, KP), dim3(256), 0, stream, hg, w2t, pw, part);
  hipLaunchKernelGGL(reduce_k, dim3(2048), dim3(256), 0, stream, part, out);
}

// Round 16
// 273.434 us; speedup vs baseline: 1.4060x; 1.4060x over previous
//
#include <hip/hip_runtime.h>
#include <stdint.h>

#define GAS __attribute__((address_space(1)))
#define LAS __attribute__((address_space(3)))

typedef __attribute__((ext_vector_type(8))) short short8;
typedef __attribute__((ext_vector_type(16))) float f32x16;

static constexpr int N_TOK = 2048;
static constexpr int DM    = 1024;
static constexpr int DF    = 4096;
static constexpr int KP    = 4;

// ---------- helpers ----------
__device__ inline unsigned short f2bf(float f) {
  union { float f; uint32_t u; } v; v.f = f;
  uint32_t u = v.u;
  u += 0x7FFFu + ((u >> 16) & 1u);   // RNE
  return (unsigned short)(u >> 16);
}

__device__ inline uint32_t pk_bf(float lo, float hi) {
  union { float f; uint32_t u; } a, b; a.f = lo; b.f = hi;
  uint32_t ul = a.u + 0x7FFFu + ((a.u >> 16) & 1u);
  uint32_t uh = b.u + 0x7FFFu + ((b.u >> 16) & 1u);
  return (ul >> 16) | (uh & 0xFFFF0000u);
}

// gelu(v)*g, sigmoid form, overflow-safe
__device__ inline float gelu_gate(float v, float g) {
  float t0 = v * v;
  float u  = v * __builtin_fmaf(t0, -0.10294456f, -2.3022539f);
  float e  = __builtin_amdgcn_exp2f(u);
  float r  = __builtin_amdgcn_rcpf(1.0f + e);
  return v * g * r;
}

__device__ inline void gld16(const void* g, void* l) {
  __builtin_amdgcn_global_load_lds((const GAS void*)g, (LAS void*)l, 16, 0, 0);
}

// ---------- fused setup ----------
// blocks [0,1024):    build_w1, block=(k, x, y-quad of 16)
// blocks [1024,1280): build_w2, block=(k, x, y-half of 16)
// blocks [1280,1792): prep (gates + bf16 cast)
// Staging y-contiguous (coalesced 64B lines), transposed into LDS.
// Compute: lean per-thread shape (one a, float4 acc) looping y in time — no spills.
// FMA order over r ascending => bit-identical weights across rounds.
__global__ __launch_bounds__(256) void setup_kernel(
    const float* __restrict__ tokens, const float* __restrict__ pb,
    const float* __restrict__ c11, const float* __restrict__ c12,
    const float* __restrict__ c21, const float* __restrict__ c22,
    float* __restrict__ gates, unsigned short* __restrict__ xb,
    unsigned short* __restrict__ w1t, unsigned short* __restrict__ w2t) {
  __shared__ __align__(16) float sh[17472];   // 69888 B
  const int blk = blockIdx.x;
  const int t = threadIdx.x;
  if (blk < 1024) {
    // ---- build_w1: w1t[k][f=x*64+y][d=a*32+b] ----
    const int k = blk >> 8, x = (blk >> 2) & 63, y0 = (blk & 3) * 16;
    float* s1  = sh;          // [a(32)][r(16)]
    float* s2T = sh + 512;    // [y(16)][stride 524], idx = r*32+b
    if (t < 128) {
      int a = t >> 2, rq = (t & 3) * 4;
      *(float4*)(s1 + a * 16 + rq) =
          *(const float4*)(c11 + (((size_t)(k * 32 + a)) * 64 + x) * 16 + rq);
    }
#pragma unroll
    for (int j = 0; j < 8; ++j) {
      int i = t + j * 256;              // [0,2048)
      int rb = i >> 2, yy0 = (i & 3) * 4;
      float4 v = *(const float4*)(c12 + (size_t)(k * 16) * 2048 + (size_t)rb * 64 + y0 + yy0);
      s2T[(yy0 + 0) * 524 + rb] = v.x;
      s2T[(yy0 + 1) * 524 + rb] = v.y;
      s2T[(yy0 + 2) * 524 + rb] = v.z;
      s2T[(yy0 + 3) * 524 + rb] = v.w;
    }
    __syncthreads();
    const int a = t >> 3, b0 = (t & 7) * 4;   // d = 4t (contiguous stores)
    float4 s1q[4];
#pragma unroll
    for (int q = 0; q < 4; ++q) s1q[q] = *(const float4*)(s1 + a * 16 + q * 4);
    const float* a0s = (const float*)s1q;
    for (int y = 0; y < 16; ++y) {
      const float* s2y = s2T + y * 524;
      float4 acc = {0.f, 0.f, 0.f, 0.f};
#pragma unroll
      for (int r = 0; r < 16; ++r) {
        float cv = a0s[r];
        float4 bv = *(const float4*)(s2y + r * 32 + b0);
        acc.x = __builtin_fmaf(cv, bv.x, acc.x);
        acc.y = __builtin_fmaf(cv, bv.y, acc.y);
        acc.z = __builtin_fmaf(cv, bv.z, acc.z);
        acc.w = __builtin_fmaf(cv, bv.w, acc.w);
      }
      ushort4 o; o.x = f2bf(acc.x); o.y = f2bf(acc.y); o.z = f2bf(acc.z); o.w = f2bf(acc.w);
      *(ushort4*)(w1t + ((size_t)k * DF + x * 64 + y0 + y) * DM + t * 4) = o;
    }
  } else if (blk < 1280) {
    // ---- build_w2: w2t[k][d=x*32+y][f=a*64+b] ----
    const int bb = blk - 1024;
    const int k = bb >> 6, x = (bb >> 1) & 31, y0 = (bb & 1) * 16;
    float* s1  = sh;           // [a(64)][r(16)]
    float* s2T = sh + 1024;    // [y(16)][stride 1028], idx = r*64+b
    {
      int a = t >> 2, rq = (t & 3) * 4;
      *(float4*)(s1 + a * 16 + rq) =
          *(const float4*)(c21 + (((size_t)(k * 64 + a)) * 32 + x) * 16 + rq);
    }
#pragma unroll
    for (int j = 0; j < 16; ++j) {
      int i = t + j * 256;              // [0,4096)
      int rb = i >> 2, yy0 = (i & 3) * 4;
      float4 v = *(const float4*)(c22 + (size_t)(k * 16) * 2048 + (size_t)rb * 32 + y0 + yy0);
      s2T[(yy0 + 0) * 1028 + rb] = v.x;
      s2T[(yy0 + 1) * 1028 + rb] = v.y;
      s2T[(yy0 + 2) * 1028 + rb] = v.z;
      s2T[(yy0 + 3) * 1028 + rb] = v.w;
    }
    __syncthreads();
    const int b0 = (t & 15) * 4;
#pragma unroll
    for (int jj = 0; jj < 4; ++jj) {
      const int a = (t >> 4) + jj * 16;  // f = a*64+b0 = 4t + jj*1024
      float4 s1q[4];
#pragma unroll
      for (int q = 0; q < 4; ++q) s1q[q] = *(const float4*)(s1 + a * 16 + q * 4);
      const float* a0s = (const float*)s1q;
      for (int y = 0; y < 16; ++y) {
        const float* s2y = s2T + y * 1028;
        float4 acc = {0.f, 0.f, 0.f, 0.f};
#pragma unroll
        for (int r = 0; r < 16; ++r) {
          float cv = a0s[r];
          float4 bv = *(const float4*)(s2y + r * 64 + b0);
          acc.x = __builtin_fmaf(cv, bv.x, acc.x);
          acc.y = __builtin_fmaf(cv, bv.y, acc.y);
          acc.z = __builtin_fmaf(cv, bv.z, acc.z);
          acc.w = __builtin_fmaf(cv, bv.w, acc.w);
        }
        ushort4 o; o.x = f2bf(acc.x); o.y = f2bf(acc.y); o.z = f2bf(acc.z); o.w = f2bf(acc.w);
        *(ushort4*)(w2t + ((size_t)k * DM + x * 32 + y0 + y) * DF + t * 4 + jj * 1024) = o;
      }
    }
  } else {
    // ---- prep: gates + bf16 cast ----
    const int wave = t >> 6, lane = t & 63;
    const int n = (blk - 1280) * 4 + wave;
    float s0 = 0.f, s1v = 0.f, s2v = 0.f, s3v = 0.f;
    const float4* tr = (const float4*)(tokens + (size_t)n * DM);
#pragma unroll
    for (int j = 0; j < 4; ++j) {
      int idx = j * 64 + lane;
      float4 tv = tr[idx];
      ushort4 b;
      b.x = f2bf(tv.x); b.y = f2bf(tv.y); b.z = f2bf(tv.z); b.w = f2bf(tv.w);
      *(ushort4*)(xb + (size_t)n * DM + idx * 4) = b;
      float4 q;
      q = ((const float4*)(pb + 0 * DM))[idx]; s0  += tv.x*q.x + tv.y*q.y + tv.z*q.z + tv.w*q.w;
      q = ((const float4*)(pb + 1 * DM))[idx]; s1v += tv.x*q.x + tv.y*q.y + tv.z*q.z + tv.w*q.w;
      q = ((const float4*)(pb + 2 * DM))[idx]; s2v += tv.x*q.x + tv.y*q.y + tv.z*q.z + tv.w*q.w;
      q = ((const float4*)(pb + 3 * DM))[idx]; s3v += tv.x*q.x + tv.y*q.y + tv.z*q.z + tv.w*q.w;
    }
#pragma unroll
    for (int off = 32; off > 0; off >>= 1) {
      s0  += __shfl_xor(s0, off);
      s1v += __shfl_xor(s1v, off);
      s2v += __shfl_xor(s2v, off);
      s3v += __shfl_xor(s3v, off);
    }
    if (lane == 0) {
      float m = fmaxf(fmaxf(s0, s1v), fmaxf(s2v, s3v));
      float e0 = __expf(s0 - m), e1 = __expf(s1v - m), e2 = __expf(s2v - m), e3 = __expf(s3v - m);
      float inv = 1.0f / (e0 + e1 + e2 + e3);
      float4 g; g.x = e0 * inv; g.y = e1 * inv; g.z = e2 * inv; g.w = e3 * inv;
      *(float4*)(gates + n * 4) = g;
    }
  }
}

// ---------- GEMM1: hg[k][n][f] = bf16(gelu(x@W1[k])*gate)
// 128x128 tile, BK=64, mfma 32x32x16. Swizzle: phys_chunk = logc ^ (row&7) ^ ((row>>3)&7).
__global__ __launch_bounds__(256) void gemm1(
    const unsigned short* __restrict__ xb, const unsigned short* __restrict__ w1t,
    const float* __restrict__ gates, unsigned short* __restrict__ hg) {
  __shared__ __align__(16) unsigned short As[128 * 64];  // xb tile  [token-row][k]
  __shared__ __align__(16) unsigned short Bs[128 * 64];  // w1t tile [f-row][k]
  const int t = threadIdx.x, lane = t & 63, wv = t >> 6;
  const int m0 = blockIdx.x * 128;   // token tile
  const int f0 = blockIdx.y * 128;   // f tile
  const int kp = blockIdx.z;
  const unsigned short* B = w1t + (size_t)kp * DF * DM;
  f32x16 acc[2][2] = {};             // [f-frag][token-frag]
  const int srow = t >> 3;
  const int sbase = ((t & 7) ^ (srow & 7) ^ (srow >> 3)) * 8;  // elements, even i
  const int wfrow = (wv >> 1) * 64, wtcol = (wv & 1) * 64;
  const int l31 = lane & 31, khalf = lane >> 5;
  const int rsw = (l31 & 7) ^ (l31 >> 3);   // read swizzle base
  char* AsB = (char*)As;
  char* BsB = (char*)Bs;
  for (int k0 = 0; k0 < DM; k0 += 64) {
#pragma unroll
    for (int i = 0; i < 4; ++i) {
      int row = i * 32 + srow;
      int sc = sbase ^ ((i & 1) * 32);
      gld16(xb + (size_t)(m0 + row) * DM + k0 + sc, AsB + i * 4096 + t * 16);
      gld16(B + (size_t)(f0 + row) * DM + k0 + sc, BsB + i * 4096 + t * 16);
    }
    __syncthreads();
#pragma unroll
    for (int s = 0; s < 4; ++s) {
      const int lc = s * 2 + khalf;
      short8 a[2], b[2];
#pragma unroll
      for (int mi = 0; mi < 2; ++mi) {
        const int pc = ((lc ^ rsw ^ (mi * 4)) & 7) * 8;
        a[mi] = *(const short8*)(Bs + (wfrow + mi * 32 + l31) * 64 + pc);
      }
#pragma unroll
      for (int ni = 0; ni < 2; ++ni) {
        const int pc = ((lc ^ rsw ^ (ni * 4)) & 7) * 8;
        b[ni] = *(const short8*)(As + (wtcol + ni * 32 + l31) * 64 + pc);
      }
#pragma unroll
      for (int mi = 0; mi < 2; ++mi)
#pragma unroll
        for (int ni = 0; ni < 2; ++ni)
          acc[mi][ni] = __builtin_amdgcn_mfma_f32_32x32x16_bf16(a[mi], b[ni], acc[mi][ni], 0, 0, 0);
    }
    __syncthreads();
  }
  // epilogue: r-group gq holds 4 consecutive f at f = base + 8*gq
  unsigned short* H = hg + (size_t)kp * N_TOK * DF;
  const int rbase = 4 * khalf;
#pragma unroll
  for (int ni = 0; ni < 2; ++ni) {
    int n_g = m0 + wtcol + ni * 32 + l31;
    float g = gates[n_g * 4 + kp];
    unsigned short* hrow = H + (size_t)n_g * DF + f0;
#pragma unroll
    for (int mi = 0; mi < 2; ++mi) {
      int fbase = wfrow + mi * 32 + rbase;
#pragma unroll
      for (int gq = 0; gq < 4; ++gq) {
        float r0 = gelu_gate(acc[mi][ni][4 * gq + 0], g);
        float r1 = gelu_gate(acc[mi][ni][4 * gq + 1], g);
        float r2 = gelu_gate(acc[mi][ni][4 * gq + 2], g);
        float r3 = gelu_gate(acc[mi][ni][4 * gq + 3], g);
        uint2 p; p.x = pk_bf(r0, r1); p.y = pk_bf(r2, r3);
        *(uint2*)(hrow + fbase + 8 * gq) = p;
      }
    }
  }
}

// ---------- GEMM2: part[k][n][d] = (1+pw[k,d]) * (hg[k]@W2[k])[n,d]
// 128x128 tile, full K=4096, kp on z, mfma 32x32x16, same swizzle.
__global__ __launch_bounds__(256) void gemm2(
    const unsigned short* __restrict__ hg, const unsigned short* __restrict__ w2t,
    const float* __restrict__ pw, float* __restrict__ part) {
  __shared__ __align__(16) unsigned short As[128 * 64];  // hg tile  [token-row][k]
  __shared__ __align__(16) unsigned short Bs[128 * 64];  // w2t tile [d-row][k]
  const int t = threadIdx.x, lane = t & 63, wv = t >> 6;
  const int m0 = blockIdx.x * 128;   // token tile
  const int n0 = blockIdx.y * 128;   // d tile
  const int kp = blockIdx.z;
  const unsigned short* A = hg + (size_t)kp * N_TOK * DF;
  const unsigned short* B = w2t + (size_t)kp * DM * DF;
  f32x16 acc[2][2] = {};             // [d-frag][token-frag]
  const int srow = t >> 3;
  const int sbase = ((t & 7) ^ (srow & 7) ^ (srow >> 3)) * 8;
  const int wdrow = (wv >> 1) * 64, wtcol = (wv & 1) * 64;
  const int l31 = lane & 31, khalf = lane >> 5;
  const int rsw = (l31 & 7) ^ (l31 >> 3);
  char* AsB = (char*)As;
  char* BsB = (char*)Bs;
  for (int k0 = 0; k0 < DF; k0 += 64) {
#pragma unroll
    for (int i = 0; i < 4; ++i) {
      int row = i * 32 + srow;
      int sc = sbase ^ ((i & 1) * 32);
      gld16(A + (size_t)(m0 + row) * DF + k0 + sc, AsB + i * 4096 + t * 16);
      gld16(B + (size_t)(n0 + row) * DF + k0 + sc, BsB + i * 4096 + t * 16);
    }
    __syncthreads();
#pragma unroll
    for (int s = 0; s < 4; ++s) {
      const int lc = s * 2 + khalf;
      short8 a[2], b[2];
#pragma unroll
      for (int mi = 0; mi < 2; ++mi) {
        const int pc = ((lc ^ rsw ^ (mi * 4)) & 7) * 8;
        a[mi] = *(const short8*)(Bs + (wdrow + mi * 32 + l31) * 64 + pc);
      }
#pragma unroll
      for (int ni = 0; ni < 2; ++ni) {
        const int pc = ((lc ^ rsw ^ (ni * 4)) & 7) * 8;
        b[ni] = *(const short8*)(As + (wtcol + ni * 32 + l31) * 64 + pc);
      }
#pragma unroll
      for (int mi = 0; mi < 2; ++mi)
#pragma unroll
        for (int ni = 0; ni < 2; ++ni)
          acc[mi][ni] = __builtin_amdgcn_mfma_f32_32x32x16_bf16(a[mi], b[ni], acc[mi][ni], 0, 0, 0);
    }
    __syncthreads();
  }
  // epilogue: r-group gq holds 4 consecutive d at d = base + 8*gq; scale, float4 store
  float* P = part + (size_t)kp * N_TOK * DM;
  const int rbase = 4 * khalf;
  float4 pwv[2][4];
#pragma unroll
  for (int mi = 0; mi < 2; ++mi)
#pragma unroll
    for (int gq = 0; gq < 4; ++gq) {
      float4 w = *(const float4*)(pw + kp * DM + n0 + wdrow + mi * 32 + rbase + 8 * gq);
      pwv[mi][gq].x = 1.0f + w.x; pwv[mi][gq].y = 1.0f + w.y;
      pwv[mi][gq].z = 1.0f + w.z; pwv[mi][gq].w = 1.0f + w.w;
    }
#pragma unroll
  for (int ni = 0; ni < 2; ++ni) {
    int tok = m0 + wtcol + ni * 32 + l31;
    float* prow = P + (size_t)tok * DM + n0;
#pragma unroll
    for (int mi = 0; mi < 2; ++mi) {
      int dbase = wdrow + mi * 32 + rbase;
#pragma unroll
      for (int gq = 0; gq < 4; ++gq) {
        float4 o;
        o.x = pwv[mi][gq].x * acc[mi][ni][4 * gq + 0];
        o.y = pwv[mi][gq].y * acc[mi][ni][4 * gq + 1];
        o.z = pwv[mi][gq].z * acc[mi][ni][4 * gq + 2];
        o.w = pwv[mi][gq].w * acc[mi][ni][4 * gq + 3];
        *(float4*)(prow + dbase + 8 * gq) = o;
      }
    }
  }
}

// ---------- reduce partials over k ----------
__global__ __launch_bounds__(256) void reduce_k(
    const float* __restrict__ part, float* __restrict__ out) {
  const size_t i = ((size_t)blockIdx.x * 256 + threadIdx.x) * 4;
  const size_t S = (size_t)N_TOK * DM;
  float4 a = *(const float4*)(part + i);
  float4 b = *(const float4*)(part + S + i);
  float4 c = *(const float4*)(part + 2 * S + i);
  float4 d = *(const float4*)(part + 3 * S + i);
  float4 r;
  r.x = a.x + b.x + c.x + d.x;
  r.y = a.y + b.y + c.y + d.y;
  r.z = a.z + b.z + c.z + d.z;
  r.w = a.w + b.w + c.w + d.w;
  *(float4*)(out + i) = r;
}

// ---------- launcher ----------
extern "C" void kernel_launch(void* const* d_in, const int* in_sizes, int n_in,
                              void* d_out, int out_size, void* d_ws, size_t ws_size,
                              hipStream_t stream) {
  const float* tokens = (const float*)d_in[0];
  const float* f1c1   = (const float*)d_in[1];
  const float* f1c2   = (const float*)d_in[2];
  const float* f2c1   = (const float*)d_in[3];
  const float* f2c2   = (const float*)d_in[4];
  const float* pb     = (const float*)d_in[5];
  const float* pw     = (const float*)d_in[6];
  float* out = (float*)d_out;

  char* ws = (char*)d_ws;
  unsigned short* xb  = (unsigned short*)(ws);                  //   4 MB
  unsigned short* w1t = (unsigned short*)(ws + (4ull  << 20));  //  32 MB (dead after gemm1)
  float*          part = (float*)(ws + (4ull << 20));           //  32 MB (reuses w1t)
  unsigned short* w2t = (unsigned short*)(ws + (36ull << 20));  //  32 MB
  unsigned short* hg  = (unsigned short*)(ws + (68ull << 20));  //  64 MB
  float*          gates = (float*)(ws + (132ull << 20));        //  32 KB

  hipLaunchKernelGGL(setup_kernel, dim3(1792), dim3(256), 0, stream,
                     tokens, pb, f1c1, f1c2, f2c1, f2c2, gates, xb, w1t, w2t);
  hipLaunchKernelGGL(gemm1, dim3(16, 32, KP), dim3(256), 0, stream, xb, w1t, gates, hg);
  hipLaunchKernelGGL(gemm2, dim3(16, 8, KP), dim3(256), 0, stream, hg, w2t, pw, part);
  hipLaunchKernelGGL(reduce_k, dim3(2048), dim3(256), 0, stream, part, out);
}